// Round 8
// baseline (665.540 us; speedup 1.0000x reference)
//
#include <hip/hip_runtime.h>
#include <hip/hip_bf16.h>
#include <hip/hip_cooperative_groups.h>
#include <stdint.h>

namespace cg = cooperative_groups;

#define L_ 8
#define M_ 128
#define K_ 32
#define D_ 16
#define B_ 2048
#define N_ 1024           // L_*M_
#define SLAB_ 32768       // B_*D_ elements per node slab

// Clang-native 4-float vector for nontemporal builtins (HIP float4 is a class
// type the builtin rejects).
typedef float nfloat4 __attribute__((ext_vector_type(4)));

// Workspace float arena layout (offsets in floats):
#define WSF_XT    0u                          // xT[f][b]            : 32768
#define WSF_TRT   32768u                      // traceT[n][f][b]     : 33554432
#define WSF_OUTT  (32768u + 33554432u)        // outT[n<896][f][b]   : 29360128
#define WSF_WT    (WSF_OUTT + 29360128u)      // Wt[n][k][d]         : 524288
#define WSF_TOTAL (WSF_WT + 524288u)          // 63471616 floats
// meta (uint32, N_*K_ entries) lives right after the float arena.
#define WS_NEED_BYTES ((size_t)WSF_TOTAL * 4 + (size_t)N_ * K_ * 4)

// ===========================================================================
// v7b: single cooperative dispatch (round-6 design, compile fix only).
// Phase 0 = transpose + prep in-kernel; then 8 layers with grid.sync().
// 256 blocks x 1024 thr x 128 KiB LDS (1 block/CU co-resident).
//   - bt = bid & 127, mh = bid >> 7 -> half-layer block pair (bid, bid+128)
//     lands on the SAME XCD (128 % 8 == 0): state gathers hit that L2.
//   - native `out` written with nontemporal stores (write-only stream does
//     not evict traceT/outT from L3).
//   - zero inter-kernel launch/drain overhead.
// Gather / FMA / store bodies identical to verified layer6_kernel.
// ===========================================================================

__global__ __launch_bounds__(1024) void mega_kernel(
    const float* __restrict__ x, const float* __restrict__ trace,
    const int* __restrict__ sn, const int* __restrict__ sf,
    const float* __restrict__ W, const float* __restrict__ bias,
    float* __restrict__ wsf, float* __restrict__ out)
{
    extern __shared__ float G[];      // layers: [32][64][16] = 131072 B
    cg::grid_group grid = cg::this_grid();

    int tid = threadIdx.x;
    int bid = blockIdx.x;

    // ---------------- Phase 0a: transpose trace + x into arena --------------
    // 1024 tile-engines of 256 threads (4 per block); 33 predicated iters.
    {
        int eng = (bid << 2) + (tid >> 8);
        int t   = tid & 255;
        float* lds = G + (tid >> 8) * 1040;    // private [16][65] per engine
        int b  = t >> 2;
        int dq = t & 3;
        int d  = t >> 4;
        int bq = t & 15;
        for (int i = 0; i < 33; ++i) {
            int blk = (i << 10) + eng;
            bool active = blk < N_ * 32 + 32;
            const float* src = nullptr;
            float* dst = nullptr;
            int bt = 0;
            if (active) {
                if (blk < N_ * 32) {
                    int n = blk >> 5;
                    src = trace + (size_t)n * SLAB_;
                    dst = wsf + WSF_TRT + (size_t)n * SLAB_;
                    bt  = blk & 31;
                } else {
                    src = x;
                    dst = wsf + WSF_XT;
                    bt  = blk - N_ * 32;
                }
                int b0 = bt * 64;
                float4 v = ((const float4*)src)[(size_t)(b0 + b) * 4 + dq];
                lds[(dq * 4 + 0) * 65 + b] = v.x;
                lds[(dq * 4 + 1) * 65 + b] = v.y;
                lds[(dq * 4 + 2) * 65 + b] = v.z;
                lds[(dq * 4 + 3) * 65 + b] = v.w;
            }
            __syncthreads();
            if (active) {
                int b0 = bt * 64;
                float4 w4;
                w4.x = lds[d * 65 + bq * 4 + 0];
                w4.y = lds[d * 65 + bq * 4 + 1];
                w4.z = lds[d * 65 + bq * 4 + 2];
                w4.w = lds[d * 65 + bq * 4 + 3];
                ((float4*)(dst + (size_t)d * B_ + b0))[bq] = w4;
            }
            __syncthreads();
        }
    }

    // ---------------- Phase 0b: Wt transpose + meta --------------------------
    {
        uint32_t* meta = (uint32_t*)(wsf + WSF_TOTAL);
        for (int it = 0; it < 2; ++it) {
            int n = (bid << 2) + (it << 1) + (tid >> 9);   // 4 nodes per block
            int t = tid & 511;                              // t = d*32 + k
            int d = t >> 5;
            int k = t & 31;
            wsf[WSF_WT + (size_t)n * 512 + k * 16 + d] = W[(size_t)n * 512 + t];
            if (t < K_) {
                int s = sn[(size_t)n * K_ + t];
                int f = sf[(size_t)n * K_ + t];
                int l = n >> 7;
                uint32_t off;
                if (s == 0) {
                    off = WSF_XT + (uint32_t)(f * B_);
                } else if (s > (l << 7)) {
                    off = WSF_TRT + (uint32_t)((s - 1) * SLAB_ + f * B_);
                } else {
                    off = WSF_OUTT + (uint32_t)((s - 1) * SLAB_ + f * B_);
                }
                int mloc = n & 127;
                meta[((uint32_t)((l << 1) + (mloc >> 6)) << 11)
                     + (uint32_t)((t << 6) + (mloc & 63))] = off;
            }
        }
    }

    grid.sync();

    // ---------------- Layers -------------------------------------------------
    int bt2 = bid & 127;              // column tile (16 cols) — XCD-affine
    int mh  = bid >> 7;               // layer half
    int b0  = bt2 << 4;
    const uint32_t* metab = (const uint32_t*)(wsf + WSF_TOTAL);

    int m6  = tid >> 4;               // node within half
    int dq2 = (tid >> 2) & 3;         // d quarter
    int bq2 = tid & 3;                // col quad

    for (int l = 0; l < L_; ++l) {
        const uint32_t* mpl = metab + (((uint32_t)(l << 1) + mh) << 11);

        // gather: pair p = k*64+m6; 4 lanes read the pair's full 64 B line
        float4 gv[8];
#pragma unroll
        for (int jj = 0; jj < 8; ++jj) {
            uint32_t off = mpl[(jj << 8) + (tid >> 2)];
            gv[jj] = *((const float4*)(wsf + off + b0) + (tid & 3));
        }
        float4* G4 = (float4*)G;
#pragma unroll
        for (int jj = 0; jj < 8; ++jj) {
            G4[(jj << 10) + tid] = gv[jj];
        }
        __syncthreads();

        int n = (l << 7) + (mh << 6) + m6;

        float4 bv = *(const float4*)(bias + ((size_t)n << 4) + (dq2 << 2));
        float a00 = bv.x, a01 = bv.x, a02 = bv.x, a03 = bv.x;
        float a10 = bv.y, a11 = bv.y, a12 = bv.y, a13 = bv.y;
        float a20 = bv.z, a21 = bv.z, a22 = bv.z, a23 = bv.z;
        float a30 = bv.w, a31 = bv.w, a32 = bv.w, a33 = bv.w;

        const float4* wb = (const float4*)(wsf + WSF_WT + ((size_t)n << 9)) + dq2;
        const float*  gk = G + (m6 << 4) + (bq2 << 2);
#pragma unroll
        for (int k = 0; k < K_; ++k) {
            float4 g4 = *(const float4*)(gk + (k << 10));   // 4 cols
            float4 w  = wb[k << 2];                          // 4 d features
            a00 = fmaf(g4.x, w.x, a00); a01 = fmaf(g4.y, w.x, a01);
            a02 = fmaf(g4.z, w.x, a02); a03 = fmaf(g4.w, w.x, a03);
            a10 = fmaf(g4.x, w.y, a10); a11 = fmaf(g4.y, w.y, a11);
            a12 = fmaf(g4.z, w.y, a12); a13 = fmaf(g4.w, w.y, a13);
            a20 = fmaf(g4.x, w.z, a20); a21 = fmaf(g4.y, w.z, a21);
            a22 = fmaf(g4.z, w.z, a22); a23 = fmaf(g4.w, w.z, a23);
            a30 = fmaf(g4.x, w.w, a30); a31 = fmaf(g4.y, w.w, a31);
            a32 = fmaf(g4.z, w.w, a32); a33 = fmaf(g4.w, w.w, a33);
        }
        a00 = fmaxf(a00, 0.f); a01 = fmaxf(a01, 0.f); a02 = fmaxf(a02, 0.f); a03 = fmaxf(a03, 0.f);
        a10 = fmaxf(a10, 0.f); a11 = fmaxf(a11, 0.f); a12 = fmaxf(a12, 0.f); a13 = fmaxf(a13, 0.f);
        a20 = fmaxf(a20, 0.f); a21 = fmaxf(a21, 0.f); a22 = fmaxf(a22, 0.f); a23 = fmaxf(a23, 0.f);
        a30 = fmaxf(a30, 0.f); a31 = fmaxf(a31, 0.f); a32 = fmaxf(a32, 0.f); a33 = fmaxf(a33, 0.f);

        // native out: full 64 B line per (n,col); nontemporal (never re-read)
        {
            float* op = out + ((((size_t)n << 11) + b0 + (bq2 << 2)) << 4) + (dq2 << 2);
            nfloat4 v0 = {a00, a10, a20, a30};
            nfloat4 v1 = {a01, a11, a21, a31};
            nfloat4 v2 = {a02, a12, a22, a32};
            nfloat4 v3 = {a03, a13, a23, a33};
            __builtin_nontemporal_store(v0, (nfloat4*)(op));
            __builtin_nontemporal_store(v1, (nfloat4*)(op + 16));
            __builtin_nontemporal_store(v2, (nfloat4*)(op + 32));
            __builtin_nontemporal_store(v3, (nfloat4*)(op + 48));
        }

        // transposed state: full 64 B line per (n,f); cacheable (re-read)
        if (l < L_ - 1) {
            float* tp = wsf + WSF_OUTT + ((size_t)n << 15) + ((size_t)(dq2 << 2)) * B_
                      + b0 + (bq2 << 2);
            *(float4*)(tp)          = make_float4(a00, a01, a02, a03);
            *(float4*)(tp + B_)     = make_float4(a10, a11, a12, a13);
            *(float4*)(tp + 2 * B_) = make_float4(a20, a21, a22, a23);
            *(float4*)(tp + 3 * B_) = make_float4(a30, a31, a32, a33);
            grid.sync();
        }
    }
}

// ===========================================================================
// v6 MULTI-DISPATCH PATH (verified, 407 us) — used if cooperative launch
// is unavailable.
// ===========================================================================

__global__ __launch_bounds__(512) void prep6_kernel(const float* __restrict__ W,
                                                    const int* __restrict__ sn,
                                                    const int* __restrict__ sf,
                                                    float* __restrict__ wsf) {
    int n = blockIdx.x;
    int t = threadIdx.x;          // 512 = D_*K_ ; t = d*32 + k
    int d = t >> 5;
    int k = t & 31;
    wsf[WSF_WT + (size_t)n * 512 + k * 16 + d] = W[(size_t)n * 512 + t];
    if (t < K_) {
        int s = sn[(size_t)n * K_ + t];
        int f = sf[(size_t)n * K_ + t];
        int l = n >> 7;
        uint32_t off;
        if (s == 0) {
            off = WSF_XT + (uint32_t)(f * B_);
        } else if (s > (l << 7)) {
            off = WSF_TRT + (uint32_t)((s - 1) * SLAB_ + f * B_);
        } else {
            off = WSF_OUTT + (uint32_t)((s - 1) * SLAB_ + f * B_);
        }
        int mloc = n & 127;
        int mh   = mloc >> 6;
        int m6   = mloc & 63;
        uint32_t* meta = (uint32_t*)(wsf + WSF_TOTAL);
        meta[((uint32_t)((l << 1) + mh) << 11) + (uint32_t)((t << 6) + m6)] = off;
    }
}

__global__ __launch_bounds__(1024) void layer6_kernel(
    int l, float* __restrict__ wsf, const float* __restrict__ bias,
    float* __restrict__ out)
{
    extern __shared__ float G[];      // [32][64][16] floats = 131072 B

    int tid = threadIdx.x;
    int mh  = blockIdx.x & 1;
    int bt  = blockIdx.x >> 1;
    int b0  = bt << 4;

    const uint32_t* mpl = (const uint32_t*)(wsf + WSF_TOTAL)
                        + (((uint32_t)(l << 1) + mh) << 11);

    {
        float4 gv[8];
#pragma unroll
        for (int jj = 0; jj < 8; ++jj) {
            uint32_t off = mpl[(jj << 8) + (tid >> 2)];
            gv[jj] = *((const float4*)(wsf + off + b0) + (tid & 3));
        }
        float4* G4 = (float4*)G;
#pragma unroll
        for (int jj = 0; jj < 8; ++jj) {
            G4[(jj << 10) + tid] = gv[jj];
        }
    }
    __syncthreads();

    int m6 = tid >> 4;
    int dq = (tid >> 2) & 3;
    int bq = tid & 3;
    int n  = (l << 7) + (mh << 6) + m6;

    float4 bv = *(const float4*)(bias + ((size_t)n << 4) + (dq << 2));
    float a00 = bv.x, a01 = bv.x, a02 = bv.x, a03 = bv.x;
    float a10 = bv.y, a11 = bv.y, a12 = bv.y, a13 = bv.y;
    float a20 = bv.z, a21 = bv.z, a22 = bv.z, a23 = bv.z;
    float a30 = bv.w, a31 = bv.w, a32 = bv.w, a33 = bv.w;

    const float4* wb = (const float4*)(wsf + WSF_WT + ((size_t)n << 9)) + dq;
    const float*  gk = G + (m6 << 4) + (bq << 2);
#pragma unroll
    for (int k = 0; k < K_; ++k) {
        float4 g4 = *(const float4*)(gk + (k << 10));
        float4 w  = wb[k << 2];
        a00 = fmaf(g4.x, w.x, a00); a01 = fmaf(g4.y, w.x, a01);
        a02 = fmaf(g4.z, w.x, a02); a03 = fmaf(g4.w, w.x, a03);
        a10 = fmaf(g4.x, w.y, a10); a11 = fmaf(g4.y, w.y, a11);
        a12 = fmaf(g4.z, w.y, a12); a13 = fmaf(g4.w, w.y, a13);
        a20 = fmaf(g4.x, w.z, a20); a21 = fmaf(g4.y, w.z, a21);
        a22 = fmaf(g4.z, w.z, a22); a23 = fmaf(g4.w, w.z, a23);
        a30 = fmaf(g4.x, w.w, a30); a31 = fmaf(g4.y, w.w, a31);
        a32 = fmaf(g4.z, w.w, a32); a33 = fmaf(g4.w, w.w, a33);
    }
    a00 = fmaxf(a00, 0.f); a01 = fmaxf(a01, 0.f); a02 = fmaxf(a02, 0.f); a03 = fmaxf(a03, 0.f);
    a10 = fmaxf(a10, 0.f); a11 = fmaxf(a11, 0.f); a12 = fmaxf(a12, 0.f); a13 = fmaxf(a13, 0.f);
    a20 = fmaxf(a20, 0.f); a21 = fmaxf(a21, 0.f); a22 = fmaxf(a22, 0.f); a23 = fmaxf(a23, 0.f);
    a30 = fmaxf(a30, 0.f); a31 = fmaxf(a31, 0.f); a32 = fmaxf(a32, 0.f); a33 = fmaxf(a33, 0.f);

    {
        float* op = out + ((((size_t)n << 11) + b0 + (bq << 2)) << 4) + (dq << 2);
        *(float4*)(op)      = make_float4(a00, a10, a20, a30);
        *(float4*)(op + 16) = make_float4(a01, a11, a21, a31);
        *(float4*)(op + 32) = make_float4(a02, a12, a22, a32);
        *(float4*)(op + 48) = make_float4(a03, a13, a23, a33);
    }

    if (l < L_ - 1) {
        float* tp = wsf + WSF_OUTT + ((size_t)n << 15) + ((size_t)(dq << 2)) * B_
                  + b0 + (bq << 2);
        *(float4*)(tp)          = make_float4(a00, a01, a02, a03);
        *(float4*)(tp + B_)     = make_float4(a10, a11, a12, a13);
        *(float4*)(tp + 2 * B_) = make_float4(a20, a21, a22, a23);
        *(float4*)(tp + 3 * B_) = make_float4(a30, a31, a32, a33);
    }
}

__global__ __launch_bounds__(256) void transpose_bd(const float* __restrict__ trace,
                                                    const float* __restrict__ x,
                                                    float* __restrict__ traceT,
                                                    float* __restrict__ xT) {
    int blk = blockIdx.x;
    const float* src;
    float* dst;
    int bt;
    if (blk < N_ * 32) {
        int n = blk >> 5;
        src = trace + (size_t)n * SLAB_;
        dst = traceT + (size_t)n * SLAB_;
        bt  = blk & 31;
    } else {
        src = x;
        dst = xT;
        bt  = blk - N_ * 32;
    }
    int b0 = bt * 64;

    __shared__ float lds[D_][65];

    int tid = threadIdx.x;
    const float4* s4 = (const float4*)src;
    int b  = tid >> 2;
    int dq = tid & 3;
    float4 v = s4[(size_t)(b0 + b) * 4 + dq];
    lds[dq * 4 + 0][b] = v.x;
    lds[dq * 4 + 1][b] = v.y;
    lds[dq * 4 + 2][b] = v.z;
    lds[dq * 4 + 3][b] = v.w;
    __syncthreads();

    int d  = tid >> 4;
    int bq = tid & 15;
    float4 w;
    w.x = lds[d][bq * 4 + 0];
    w.y = lds[d][bq * 4 + 1];
    w.z = lds[d][bq * 4 + 2];
    w.w = lds[d][bq * 4 + 3];
    ((float4*)(dst + (size_t)d * B_ + b0))[bq] = w;
}

// ===========================================================================
// TIERED FALLBACK (no-workspace-safe, verified)
// ===========================================================================

__global__ __launch_bounds__(256) void layer_kernel(
    int l,
    const float* __restrict__ xbuf, int xfs, int xbs,
    const float* __restrict__ tbuf, int tfs, int tbs,
    const float* __restrict__ obuf, int ofs, int obs,
    const int* __restrict__ sn, const int* __restrict__ sf,
    const float* __restrict__ W, const float* __restrict__ bias,
    float* __restrict__ out, float* __restrict__ outT, int writeT)
{
    int m  = blockIdx.x >> 3;
    int bt = blockIdx.x & 7;
    int n  = l * M_ + m;
    int b  = bt * 256 + threadIdx.x;

    __shared__ float        Wsh[D_][K_];
    __shared__ float        bsh[D_];
    __shared__ const float* colp[K_];
    __shared__ int          colbs[K_];
    __shared__ float        osh[256][17];

    int tid = threadIdx.x;

    if (tid < 128) {
        ((float4*)&Wsh[0][0])[tid] = ((const float4*)(W + (size_t)n * D_ * K_))[tid];
    }
    if (tid < D_) bsh[tid] = bias[(size_t)n * D_ + tid];
    if (tid < K_) {
        int s = sn[(size_t)n * K_ + tid];
        int f = sf[(size_t)n * K_ + tid];
        const float* p;
        int bs;
        if (s == 0) {
            p  = xbuf + (size_t)f * xfs;
            bs = xbs;
        } else {
            int ls = (s - 1) >> 7;
            if (ls >= l) {
                p  = tbuf + (size_t)(s - 1) * SLAB_ + (size_t)f * tfs;
                bs = tbs;
            } else {
                p  = obuf + (size_t)(s - 1) * SLAB_ + (size_t)f * ofs;
                bs = obs;
            }
        }
        colp[tid]  = p;
        colbs[tid] = bs;
    }
    __syncthreads();

    float g[K_];
#pragma unroll
    for (int k = 0; k < K_; ++k) {
        g[k] = colp[k][(size_t)b * colbs[k]];
    }

#pragma unroll
    for (int d = 0; d < D_; ++d) {
        float acc = bsh[d];
#pragma unroll
        for (int k = 0; k < K_; ++k) acc = fmaf(g[k], Wsh[d][k], acc);
        acc = fmaxf(acc, 0.0f);
        osh[tid][d] = acc;
        if (writeT) outT[(size_t)n * SLAB_ + (size_t)d * B_ + b] = acc;
    }
    __syncthreads();

    float4* region4 = (float4*)(out + (size_t)n * SLAB_ + (size_t)(bt * 256) * D_);
#pragma unroll
    for (int j = 0; j < 4; ++j) {
        int i   = j * 256 + tid;
        int row = i >> 2;
        int c0  = (i & 3) * 4;
        float4 w;
        w.x = osh[row][c0 + 0];
        w.y = osh[row][c0 + 1];
        w.z = osh[row][c0 + 2];
        w.w = osh[row][c0 + 3];
        region4[i] = w;
    }
}

extern "C" void kernel_launch(void* const* d_in, const int* in_sizes, int n_in,
                              void* d_out, int out_size, void* d_ws, size_t ws_size,
                              hipStream_t stream) {
    const float* x     = (const float*)d_in[0];
    const float* trace = (const float*)d_in[1];
    const int*   sn    = (const int*)d_in[2];
    const int*   sf    = (const int*)d_in[3];
    const float* W     = (const float*)d_in[4];
    const float* bias  = (const float*)d_in[5];
    float*       out   = (float*)d_out;

    static int mode = -1;   // 2 = cooperative mega, 1 = v6 multi-dispatch, 0 = tiers
    if (mode < 0) {
        hipError_t e1 = hipFuncSetAttribute(
            reinterpret_cast<const void*>(mega_kernel),
            hipFuncAttributeMaxDynamicSharedMemorySize, 131072);
        hipError_t e2 = hipFuncSetAttribute(
            reinterpret_cast<const void*>(layer6_kernel),
            hipFuncAttributeMaxDynamicSharedMemorySize, 131072);
        (void)hipGetLastError();
        if (e1 == hipSuccess)      mode = 2;
        else if (e2 == hipSuccess) mode = 1;
        else                       mode = 0;
    }

    if (mode >= 1 && ws_size >= WS_NEED_BYTES) {
        float* wsf = (float*)d_ws;

        if (mode == 2) {
            void* args[] = {(void*)&x, (void*)&trace, (void*)&sn, (void*)&sf,
                            (void*)&W, (void*)&bias, (void*)&wsf, (void*)&out};
            hipError_t e = hipLaunchCooperativeKernel(
                reinterpret_cast<const void*>(mega_kernel),
                dim3(256), dim3(1024), args, 131072u, stream);
            if (e == hipSuccess) return;
            (void)hipGetLastError();
            mode = 1;   // demote permanently, fall through
        }

        transpose_bd<<<N_ * 32 + 32, 256, 0, stream>>>(trace, x,
                                                       wsf + WSF_TRT, wsf + WSF_XT);
        prep6_kernel<<<N_, 512, 0, stream>>>(W, sn, sf, wsf);
        for (int l = 0; l < L_; ++l) {
            layer6_kernel<<<256, 1024, 131072, stream>>>(l, wsf, bias, out);
        }
        return;
    }

    // ---------------- tiered fallback ----------------
    const size_t xT_elems  = (size_t)D_ * B_;
    const size_t big_elems = (size_t)N_ * SLAB_;
    const size_t needA = sizeof(float) * (xT_elems + 2 * big_elems);
    const size_t needB = sizeof(float) * (xT_elems + 1 * big_elems);

    float* ws = (float*)d_ws;

    if (ws_size >= needA) {
        float* xT     = ws;
        float* traceT = ws + xT_elems;
        float* outT   = traceT + big_elems;

        transpose_bd<<<N_ * 32 + 32, 256, 0, stream>>>(trace, x, traceT, xT);
        for (int l = 0; l < L_; ++l) {
            layer_kernel<<<M_ * 8, 256, 0, stream>>>(
                l,
                xT,     B_, 1,
                traceT, B_, 1,
                outT,   B_, 1,
                sn, sf, W, bias, out, outT, 1);
        }
    } else if (ws_size >= needB) {
        float* xT     = ws;
        float* traceT = ws + xT_elems;

        transpose_bd<<<N_ * 32 + 32, 256, 0, stream>>>(trace, x, traceT, xT);
        for (int l = 0; l < L_; ++l) {
            layer_kernel<<<M_ * 8, 256, 0, stream>>>(
                l,
                xT,     B_, 1,
                traceT, B_, 1,
                out,    1,  D_,
                sn, sf, W, bias, out, nullptr, 0);
        }
    } else {
        for (int l = 0; l < L_; ++l) {
            layer_kernel<<<M_ * 8, 256, 0, stream>>>(
                l,
                x,     1, D_,
                trace, 1, D_,
                out,   1, D_,
                sn, sf, W, bias, out, nullptr, 0);
        }
    }
}